// Round 8
// baseline (471.726 us; speedup 1.0000x reference)
//
#include <hip/hip_runtime.h>
#include <hip/hip_bf16.h>
#include <math.h>

#define N_NODES 100000
#define N_PAD 100032   // padded row count for workspace feature buffers
#define N_EDGES 1600000
#define HID 128
#define N_CLASS 10

// edge partition params: 256 dst-ranges of 391 nodes (256*391 = 100096)
#define NR2 256
#define RANGE2 391
#define PCAP2 8192     // per-range packed capacity (expected ~6250, max ~6600)
#define P_BLOCKS 512
#define P_SLICE (N_EDGES / P_BLOCKS)  // 3125

typedef float f32x4 __attribute__((ext_vector_type(4)));
typedef short short8 __attribute__((ext_vector_type(8)));
typedef unsigned short us4 __attribute__((ext_vector_type(4)));

// bf16 helpers (round-to-nearest-even)
__device__ __forceinline__ unsigned short f2bf(float x) {
    unsigned u = __float_as_uint(x);
    unsigned r = u + 0x7FFF + ((u >> 16) & 1);
    return (unsigned short)(r >> 16);
}
__device__ __forceinline__ float bf2f(unsigned short h) {
    return __uint_as_float(((unsigned)h) << 16);
}
__device__ __forceinline__ float elu(float x) {
    return x > 0.f ? x : (expf(x) - 1.f);
}
__device__ __forceinline__ float4 us4f(us4 v) {
    float4 o;
    o.x = bf2f(v.x); o.y = bf2f(v.y); o.z = bf2f(v.z); o.w = bf2f(v.w);
    return o;
}

// ---------------------------------------------------------------------------
// CSR build v3: 256-way partition -> per-range LDS counting sort.
// ---------------------------------------------------------------------------

__global__ __launch_bounds__(256) void part_k(const int* __restrict__ src,
                                              const int* __restrict__ dst,
                                              int* __restrict__ gcnt,
                                              unsigned* __restrict__ gbuf) {
    __shared__ unsigned stash[P_SLICE];
    __shared__ unsigned char rbuf[P_SLICE];
    __shared__ int hist[NR2], cur[NR2], base[NR2];
    hist[threadIdx.x] = 0;
    cur[threadIdx.x] = 0;
    __syncthreads();
    const int e0 = blockIdx.x * P_SLICE;
    for (int i = threadIdx.x; i < P_SLICE; i += 256) {
        unsigned s = (unsigned)src[e0 + i];
        unsigned d = (unsigned)dst[e0 + i];
        unsigned r = d / RANGE2;            // magic-mul
        unsigned dloc = d - r * RANGE2;     // < 391 (9 bits)
        stash[i] = s | (dloc << 17);
        rbuf[i] = (unsigned char)r;
        atomicAdd(&hist[r], 1);
    }
    __syncthreads();
    base[threadIdx.x] = atomicAdd(&gcnt[threadIdx.x], hist[threadIdx.x]);
    __syncthreads();
    for (int i = threadIdx.x; i < P_SLICE; i += 256) {
        unsigned r = rbuf[i];
        int off = atomicAdd(&cur[r], 1);
        int pos = base[r] + off;
        if (pos < PCAP2) gbuf[(size_t)r * PCAP2 + pos] = stash[i];
    }
}

__global__ void scanc_k(const int* __restrict__ gcnt, int* __restrict__ colbase,
                        int* __restrict__ row_ptr) {
    __shared__ int sh[NR2];
    int v = gcnt[threadIdx.x];
    sh[threadIdx.x] = v;
    __syncthreads();
    for (int off = 1; off < NR2; off <<= 1) {
        int t = (threadIdx.x >= off) ? sh[threadIdx.x - off] : 0;
        __syncthreads();
        sh[threadIdx.x] += t;
        __syncthreads();
    }
    colbase[threadIdx.x] = sh[threadIdx.x] - v;  // exclusive
    if (threadIdx.x == 0) row_ptr[N_NODES] = N_EDGES;
}

__global__ __launch_bounds__(256) void csort_k(const unsigned* __restrict__ gbuf,
                                               const int* __restrict__ gcnt,
                                               const int* __restrict__ colbase,
                                               int* __restrict__ row_ptr,
                                               int* __restrict__ col) {
    __shared__ int sorted[PCAP2];   // 32 KB
    __shared__ int hist[512];
    __shared__ int cnt[512];
    __shared__ int run[400];
    const int q = blockIdx.x;
    const int tid = threadIdx.x;
    const int n2 = gcnt[q];
    const int cb = colbase[q];
    const int node0 = q * RANGE2;
    const unsigned* buf = gbuf + (size_t)q * PCAP2;

    hist[tid] = 0; hist[tid + 256] = 0;
    __syncthreads();
    for (int i = tid; i < n2; i += 256)
        atomicAdd(&hist[buf[i] >> 17], 1);
    __syncthreads();
    cnt[tid] = hist[tid];
    cnt[tid + 256] = hist[tid + 256];
    __syncthreads();
    for (int off = 1; off < 512; off <<= 1) {
        int v0 = (tid >= off) ? hist[tid - off] : 0;
        int v1 = hist[tid + 256 - off];
        __syncthreads();
        hist[tid] += v0;
        hist[tid + 256] += v1;
        __syncthreads();
    }
#pragma unroll
    for (int b = 0; b < 2; b++) {
        int i = tid + 256 * b;
        if (i < RANGE2) {
            int excl = hist[i] - cnt[i];
            run[i] = excl;
            int node = node0 + i;
            if (node < N_NODES) row_ptr[node] = cb + excl;
        }
    }
    __syncthreads();
    for (int i = tid; i < n2; i += 256) {
        unsigned w = buf[i];
        int pos = atomicAdd(&run[w >> 17], 1);
        sorted[pos] = (int)(w & 0x1FFFF);
    }
    __syncthreads();
    for (int i = tid; i < n2; i += 256) col[cb + i] = sorted[i];
}

// ---------------------------------------------------------------------------
// fp32 -> bf16 cast of x (layer-1 gather source)
// ---------------------------------------------------------------------------
__global__ __launch_bounds__(256) void cast_k(const float* __restrict__ x,
                                              unsigned short* __restrict__ hb) {
    int i = blockIdx.x * blockDim.x + threadIdx.x;  // float4 index
    if (i < N_NODES * (HID / 4)) {
        float4 v = ((const float4*)x)[i];
        us4 o = {f2bf(v.x), f2bf(v.y), f2bf(v.z), f2bf(v.w)};
        ((us4*)hb)[i] = o;
    }
}

// ---------------------------------------------------------------------------
// Weight pre-split + pre-pack into MFMA B-fragment order.
// ---------------------------------------------------------------------------
__global__ void wsplit_k(const float* __restrict__ Wa, const float* __restrict__ Wb,
                         unsigned short* __restrict__ Whp,
                         unsigned short* __restrict__ Wlp) {
    int f = blockIdx.x * blockDim.x + threadIdx.x;
    if (f >= 6 * 16384) return;
    int g = f >> 14;
    int r = f & 16383;
    int j = r & 7;
    int L = (r >> 3) & 63;
    int t = r >> 9;          // kb*8 + nt
    int kb = t >> 3, nt = t & 7;
    int k = kb * 32 + ((L >> 4) & 3) * 8 + j;
    int n = nt * 16 + (L & 15);
    int layer = g >> 1;
    const float* W = (g & 1) ? Wb : Wa;
    float w = W[layer * 16384 + k * 128 + n];
    unsigned short hi = f2bf(w);
    unsigned short lo = f2bf(w - bf2f(hi));
    Whp[f] = hi;
    Wlp[f] = lo;
}

// fcW [128][10] -> B-frag layout, N padded to 16.
__global__ void fcsplit_k(const float* __restrict__ fcW,
                          unsigned short* __restrict__ fcWph,
                          unsigned short* __restrict__ fcWpl) {
    int f = blockIdx.x * blockDim.x + threadIdx.x;
    if (f >= 2048) return;
    int j = f & 7;
    int L = (f >> 3) & 63;
    int kb = f >> 9;
    int k = kb * 32 + ((L >> 4) & 3) * 8 + j;
    int n = L & 15;
    float w = (n < N_CLASS) ? fcW[k * N_CLASS + n] : 0.f;
    unsigned short hi = f2bf(w);
    unsigned short lo = f2bf(w - bf2f(hi));
    fcWph[f] = hi;
    fcWpl[f] = lo;
}

// ---------------------------------------------------------------------------
// Fused layer: gather z (GIN agg, fp32 acc) -> split-bf16 MFMA MLP -> h or FC.
// 64 nodes/block; 8 half-waves gather 8 nodes each into registers, pack into
// A-frag LDS directly (no zbuf round-trip). hin/hout must be distinct buffers.
// ---------------------------------------------------------------------------
__device__ __forceinline__ void gemm_phase(
    const unsigned short* Aph_, const unsigned short* Apl_,
    const unsigned short* __restrict__ Whi_g,
    const unsigned short* __restrict__ Wlo_g,
    const float* __restrict__ bias, int tid, f32x4 acc[2][4]) {
    const int L = tid & 63;
    const int w = tid >> 6;
    const int mt0 = (w >> 1) * 2;
    const int nt0 = (w & 1) * 4;
    const int lan15 = L & 15;
#pragma unroll
    for (int n = 0; n < 4; n++) {
        float b = bias[(nt0 + n) * 16 + lan15];
        f32x4 bv = {b, b, b, b};
        acc[0][n] = bv;
        acc[1][n] = bv;
    }
#pragma unroll
    for (int kb = 0; kb < 4; kb++) {
        short8 ah0 = *(const short8*)&Aph_[(((mt0 + 0) * 4 + kb) * 64 + L) * 8];
        short8 ah1 = *(const short8*)&Aph_[(((mt0 + 1) * 4 + kb) * 64 + L) * 8];
        short8 al0 = *(const short8*)&Apl_[(((mt0 + 0) * 4 + kb) * 64 + L) * 8];
        short8 al1 = *(const short8*)&Apl_[(((mt0 + 1) * 4 + kb) * 64 + L) * 8];
#pragma unroll
        for (int n = 0; n < 4; n++) {
            int widx = ((kb * 8 + nt0 + n) * 64 + L) * 8;
            short8 bh = *(const short8*)&Whi_g[widx];
            short8 bl = *(const short8*)&Wlo_g[widx];
            acc[0][n] = __builtin_amdgcn_mfma_f32_16x16x32_bf16(ah0, bh, acc[0][n], 0, 0, 0);
            acc[1][n] = __builtin_amdgcn_mfma_f32_16x16x32_bf16(ah1, bh, acc[1][n], 0, 0, 0);
            acc[0][n] = __builtin_amdgcn_mfma_f32_16x16x32_bf16(al0, bh, acc[0][n], 0, 0, 0);
            acc[1][n] = __builtin_amdgcn_mfma_f32_16x16x32_bf16(al1, bh, acc[1][n], 0, 0, 0);
            acc[0][n] = __builtin_amdgcn_mfma_f32_16x16x32_bf16(ah0, bl, acc[0][n], 0, 0, 0);
            acc[1][n] = __builtin_amdgcn_mfma_f32_16x16x32_bf16(ah1, bl, acc[1][n], 0, 0, 0);
        }
    }
}

template <int FC>
__device__ __forceinline__ void layer_body(
    const unsigned short* __restrict__ hin,
    const int* __restrict__ row_ptr, const int* __restrict__ col,
    const unsigned short* __restrict__ Wahp, const unsigned short* __restrict__ Walp,
    const unsigned short* __restrict__ Wbhp, const unsigned short* __restrict__ Wblp,
    const float* __restrict__ ba, const float* __restrict__ bb,
    unsigned short* __restrict__ hout,
    const unsigned short* __restrict__ fcWph, const unsigned short* __restrict__ fcWpl,
    const float* __restrict__ fcb, float* __restrict__ out) {
    __shared__ unsigned short Aph[8192];   // 16 KB: packed A hi
    __shared__ unsigned short Apl[8192];   // 16 KB: packed A lo

    const int tid = threadIdx.x;
    const int L = tid & 63;
    const int w = tid >> 6;
    const int mt0 = (w >> 1) * 2;
    const int nt0 = (w & 1) * 4;
    const int lan15 = L & 15;
    const int quad = L >> 4;
    const size_t node_base = (size_t)blockIdx.x * 64;

    // ---- fused gather + split + pack (replaces agg_k + phase A) ----
    {
        const int hwv = tid >> 5;        // half-wave 0..7
        const int lane = tid & 31;
        const int halfbase = tid & 32;   // lane offset within the wave64
        const us4* hp = (const us4*)hin;
        const int k0 = lane * 4;
        const int kb = k0 >> 5;
        const int q = (k0 & 31) >> 3;
        const int j0 = k0 & 7;
#pragma unroll 1
        for (int i = 0; i < 8; i++) {
            const int m = hwv * 8 + i;             // node slot 0..63
            const int node = (int)node_base + m;
            float4 acc = {0.f, 0.f, 0.f, 0.f};
            if (node < N_NODES) {
                acc = us4f(hp[(size_t)node * 32 + lane]);  // self term
                const int beg = row_ptr[node];
                const int end = row_ptr[node + 1];
                for (int base = beg; base < end; base += 32) {
                    const int n = min(32, end - base);
                    int myidx = (lane < n) ? col[base + lane] : 0;
                    int j = 0;
                    for (; j + 4 <= n; j += 4) {
                        int i0 = __shfl(myidx, halfbase + j + 0, 64);
                        int i1 = __shfl(myidx, halfbase + j + 1, 64);
                        int i2 = __shfl(myidx, halfbase + j + 2, 64);
                        int i3 = __shfl(myidx, halfbase + j + 3, 64);
                        float4 v0 = us4f(hp[(size_t)i0 * 32 + lane]);
                        float4 v1 = us4f(hp[(size_t)i1 * 32 + lane]);
                        float4 v2 = us4f(hp[(size_t)i2 * 32 + lane]);
                        float4 v3 = us4f(hp[(size_t)i3 * 32 + lane]);
                        acc.x += v0.x; acc.y += v0.y; acc.z += v0.z; acc.w += v0.w;
                        acc.x += v1.x; acc.y += v1.y; acc.z += v1.z; acc.w += v1.w;
                        acc.x += v2.x; acc.y += v2.y; acc.z += v2.z; acc.w += v2.w;
                        acc.x += v3.x; acc.y += v3.y; acc.z += v3.z; acc.w += v3.w;
                    }
                    for (; j < n; j++) {
                        int i0 = __shfl(myidx, halfbase + j, 64);
                        float4 v0 = us4f(hp[(size_t)i0 * 32 + lane]);
                        acc.x += v0.x; acc.y += v0.y; acc.z += v0.z; acc.w += v0.w;
                    }
                }
            }
            // split to bf16 hi/lo and write A-frag LDS slot for node m
            const int idx = (((m >> 4) * 4 + kb) * 64 + ((m & 15) + 16 * q)) * 8 + j0;
            unsigned short sx = f2bf(acc.x), sy = f2bf(acc.y),
                           sz = f2bf(acc.z), sw = f2bf(acc.w);
            us4 h4 = {sx, sy, sz, sw};
            us4 l4 = {f2bf(acc.x - bf2f(sx)), f2bf(acc.y - bf2f(sy)),
                      f2bf(acc.z - bf2f(sz)), f2bf(acc.w - bf2f(sw))};
            *(us4*)&Aph[idx] = h4;
            *(us4*)&Apl[idx] = l4;
        }
    }
    __syncthreads();

    // ---- GEMM1: t = ELU(z @ Wa + ba) ----
    {
        f32x4 acc[2][4];
        gemm_phase(Aph, Apl, Wahp, Walp, ba, tid, acc);
        __syncthreads();
#pragma unroll
        for (int i = 0; i < 2; i++) {
#pragma unroll
            for (int n = 0; n < 4; n++) {
                int kdim = (nt0 + n) * 16 + lan15;
                int kb2 = kdim >> 5;
                int q2 = (kdim & 31) >> 3;
                int j2 = kdim & 7;
#pragma unroll
                for (int r = 0; r < 4; r++) {
                    float v = elu(acc[i][n][r]);
                    int mrow = quad * 4 + r;
                    unsigned short hi = f2bf(v);
                    unsigned short lo = f2bf(v - bf2f(hi));
                    int idx = (((mt0 + i) * 4 + kb2) * 64 + (mrow + 16 * q2)) * 8 + j2;
                    Aph[idx] = hi;
                    Apl[idx] = lo;
                }
            }
        }
    }
    __syncthreads();

    // ---- GEMM2: h = ELU(t @ Wb + bb) ----
    {
        f32x4 acc[2][4];
        gemm_phase(Aph, Apl, Wbhp, Wblp, bb, tid, acc);
        if (FC == 0) {
#pragma unroll
            for (int i = 0; i < 2; i++) {
#pragma unroll
                for (int n = 0; n < 4; n++) {
                    int ncol = (nt0 + n) * 16 + lan15;
#pragma unroll
                    for (int r = 0; r < 4; r++) {
                        int mrow = (mt0 + i) * 16 + quad * 4 + r;
                        hout[(node_base + mrow) * HID + ncol] = f2bf(elu(acc[i][n][r]));
                    }
                }
            }
        } else {
            // repack h-hi (identical rounding to the stored-h path) for FC
            __syncthreads();
#pragma unroll
            for (int i = 0; i < 2; i++) {
#pragma unroll
                for (int n = 0; n < 4; n++) {
                    int kdim = (nt0 + n) * 16 + lan15;
                    int kb2 = kdim >> 5;
                    int q2 = (kdim & 31) >> 3;
                    int j2 = kdim & 7;
#pragma unroll
                    for (int r = 0; r < 4; r++) {
                        float v = elu(acc[i][n][r]);
                        int mrow = quad * 4 + r;
                        int idx = (((mt0 + i) * 4 + kb2) * 64 + (mrow + 16 * q2)) * 8 + j2;
                        Aph[idx] = f2bf(v);
                    }
                }
            }
            __syncthreads();
            // FC: waves 0 and 2 handle their 2 M-tiles vs N-tile 0
            if ((w & 1) == 0) {
#pragma unroll
                for (int i = 0; i < 2; i++) {
                    int mt = mt0 + i;
                    float b = (lan15 < N_CLASS) ? fcb[lan15] : 0.f;
                    f32x4 acc2 = {b, b, b, b};
#pragma unroll
                    for (int kb = 0; kb < 4; kb++) {
                        short8 a = *(const short8*)&Aph[((mt * 4 + kb) * 64 + L) * 8];
                        short8 bh = *(const short8*)&fcWph[(kb * 64 + L) * 8];
                        short8 bl = *(const short8*)&fcWpl[(kb * 64 + L) * 8];
                        acc2 = __builtin_amdgcn_mfma_f32_16x16x32_bf16(a, bh, acc2, 0, 0, 0);
                        acc2 = __builtin_amdgcn_mfma_f32_16x16x32_bf16(a, bl, acc2, 0, 0, 0);
                    }
#pragma unroll
                    for (int r = 0; r < 4; r++) {
                        size_t node = node_base + mt * 16 + quad * 4 + r;
                        if (node < N_NODES && lan15 < N_CLASS)
                            out[node * N_CLASS + lan15] = acc2[r];
                    }
                }
            }
        }
    }
}

__global__ __launch_bounds__(256) void layer_mid_k(
    const unsigned short* __restrict__ hin,
    const int* __restrict__ row_ptr, const int* __restrict__ col,
    const unsigned short* __restrict__ Wahp, const unsigned short* __restrict__ Walp,
    const unsigned short* __restrict__ Wbhp, const unsigned short* __restrict__ Wblp,
    const float* __restrict__ ba, const float* __restrict__ bb,
    unsigned short* __restrict__ hout) {
    layer_body<0>(hin, row_ptr, col, Wahp, Walp, Wbhp, Wblp, ba, bb, hout,
                  nullptr, nullptr, nullptr, nullptr);
}

__global__ __launch_bounds__(256) void layer_fc_k(
    const unsigned short* __restrict__ hin,
    const int* __restrict__ row_ptr, const int* __restrict__ col,
    const unsigned short* __restrict__ Wahp, const unsigned short* __restrict__ Walp,
    const unsigned short* __restrict__ Wbhp, const unsigned short* __restrict__ Wblp,
    const float* __restrict__ ba, const float* __restrict__ bb,
    const unsigned short* __restrict__ fcWph, const unsigned short* __restrict__ fcWpl,
    const float* __restrict__ fcb, float* __restrict__ out) {
    layer_body<1>(hin, row_ptr, col, Wahp, Walp, Wbhp, Wblp, ba, bb, nullptr,
                  fcWph, fcWpl, fcb, out);
}

// ---------------------------------------------------------------------------

extern "C" void kernel_launch(void* const* d_in, const int* in_sizes, int n_in,
                              void* d_out, int out_size, void* d_ws, size_t ws_size,
                              hipStream_t stream) {
    const float* x = (const float*)d_in[0];
    const int* ei = (const int*)d_in[1];  // [2][E]
    // d_in[2] = edge_weight (unused by the reference forward)
    const float* Wa = (const float*)d_in[3];   // [3][128][128]
    const float* ba = (const float*)d_in[4];   // [3][128]
    const float* Wb = (const float*)d_in[5];
    const float* bb = (const float*)d_in[6];
    const float* fcW = (const float*)d_in[7];  // [128][10]
    const float* fcb = (const float*)d_in[8];  // [10]
    float* out = (float*)d_out;

    const int* src = ei;
    const int* dst = ei + N_EDGES;

    // workspace carve
    char* w = (char*)d_ws;
    unsigned short* hbA = (unsigned short*)w; w += (size_t)N_PAD * HID * 2;
    unsigned short* hbB = (unsigned short*)w; w += (size_t)N_PAD * HID * 2;
    int* row_ptr = (int*)w;  w += ((size_t)N_NODES + 8) * 4;
    int* gcnt = (int*)w;     w += NR2 * 4;
    int* colbase = (int*)w;  w += NR2 * 4;
    int* col = (int*)w;      w += (size_t)N_EDGES * 4;
    unsigned short* Whp = (unsigned short*)w; w += 6 * 16384 * 2;
    unsigned short* Wlp = (unsigned short*)w; w += 6 * 16384 * 2;
    unsigned short* fcWph = (unsigned short*)w; w += 2048 * 2;
    unsigned short* fcWpl = (unsigned short*)w; w += 2048 * 2;
    unsigned* gbuf = (unsigned*)w; w += (size_t)NR2 * PCAP2 * 4;  // 8 MB

    // ---- weight split/pack + x cast (independent of CSR) ----
    wsplit_k<<<(6 * 16384 + 255) / 256, 256, 0, stream>>>(Wa, Wb, Whp, Wlp);
    fcsplit_k<<<8, 256, 0, stream>>>(fcW, fcWph, fcWpl);
    cast_k<<<(N_NODES * (HID / 4) + 255) / 256, 256, 0, stream>>>(x, hbA);

    // ---- CSR build v3 ----
    hipMemsetAsync(gcnt, 0, NR2 * 4, stream);
    part_k<<<P_BLOCKS, 256, 0, stream>>>(src, dst, gcnt, gbuf);
    scanc_k<<<1, 256, 0, stream>>>(gcnt, colbase, row_ptr);
    csort_k<<<NR2, 256, 0, stream>>>(gbuf, gcnt, colbase, row_ptr, col);

    const int LAYER_BLOCKS = (N_NODES + 63) / 64;  // 1563

    // ---- layer 1: hbA -> hbB ----
    layer_mid_k<<<LAYER_BLOCKS, 256, 0, stream>>>(hbA, row_ptr, col,
                                                  Whp, Wlp, Whp + 16384, Wlp + 16384,
                                                  ba, bb, hbB);
    // ---- layer 2: hbB -> hbA ----
    layer_mid_k<<<LAYER_BLOCKS, 256, 0, stream>>>(hbB, row_ptr, col,
                                                  Whp + 2 * 16384, Wlp + 2 * 16384,
                                                  Whp + 3 * 16384, Wlp + 3 * 16384,
                                                  ba + 128, bb + 128, hbA);
    // ---- layer 3: hbA -> out (fused FC) ----
    layer_fc_k<<<LAYER_BLOCKS, 256, 0, stream>>>(hbA, row_ptr, col,
                                                 Whp + 4 * 16384, Wlp + 4 * 16384,
                                                 Whp + 5 * 16384, Wlp + 5 * 16384,
                                                 ba + 256, bb + 256,
                                                 fcWph, fcWpl, fcb, out);
}

// Round 9
// 419.432 us; speedup vs baseline: 1.1247x; 1.1247x over previous
//
#include <hip/hip_runtime.h>
#include <hip/hip_bf16.h>
#include <math.h>

#define N_NODES 100000
#define N_PAD 100032   // padded row count for workspace feature buffers
#define N_EDGES 1600000
#define HID 128
#define N_CLASS 10

// edge partition params: 256 dst-ranges of 391 nodes (256*391 = 100096)
#define NR2 256
#define RANGE2 391
#define PCAP2 8192     // per-range packed capacity (expected ~6250, max ~6600)
#define P_BLOCKS 512
#define P_SLICE (N_EDGES / P_BLOCKS)  // 3125

typedef float f32x4 __attribute__((ext_vector_type(4)));
typedef short short8 __attribute__((ext_vector_type(8)));
typedef unsigned short us4 __attribute__((ext_vector_type(4)));

// bf16 helpers (round-to-nearest-even)
__device__ __forceinline__ unsigned short f2bf(float x) {
    unsigned u = __float_as_uint(x);
    unsigned r = u + 0x7FFF + ((u >> 16) & 1);
    return (unsigned short)(r >> 16);
}
__device__ __forceinline__ float bf2f(unsigned short h) {
    return __uint_as_float(((unsigned)h) << 16);
}
__device__ __forceinline__ float elu(float x) {
    return x > 0.f ? x : (expf(x) - 1.f);
}
__device__ __forceinline__ float4 us4f(us4 v) {
    float4 o;
    o.x = bf2f(v.x); o.y = bf2f(v.y); o.z = bf2f(v.z); o.w = bf2f(v.w);
    return o;
}

// ---------------------------------------------------------------------------
// CSR build v3: 256-way partition -> per-range LDS counting sort.
// ---------------------------------------------------------------------------

__global__ __launch_bounds__(256) void part_k(const int* __restrict__ src,
                                              const int* __restrict__ dst,
                                              int* __restrict__ gcnt,
                                              unsigned* __restrict__ gbuf) {
    __shared__ unsigned stash[P_SLICE];
    __shared__ unsigned char rbuf[P_SLICE];
    __shared__ int hist[NR2], cur[NR2], base[NR2];
    hist[threadIdx.x] = 0;
    cur[threadIdx.x] = 0;
    __syncthreads();
    const int e0 = blockIdx.x * P_SLICE;
    for (int i = threadIdx.x; i < P_SLICE; i += 256) {
        unsigned s = (unsigned)src[e0 + i];
        unsigned d = (unsigned)dst[e0 + i];
        unsigned r = d / RANGE2;            // magic-mul
        unsigned dloc = d - r * RANGE2;     // < 391 (9 bits)
        stash[i] = s | (dloc << 17);
        rbuf[i] = (unsigned char)r;
        atomicAdd(&hist[r], 1);
    }
    __syncthreads();
    base[threadIdx.x] = atomicAdd(&gcnt[threadIdx.x], hist[threadIdx.x]);
    __syncthreads();
    for (int i = threadIdx.x; i < P_SLICE; i += 256) {
        unsigned r = rbuf[i];
        int off = atomicAdd(&cur[r], 1);
        int pos = base[r] + off;
        if (pos < PCAP2) gbuf[(size_t)r * PCAP2 + pos] = stash[i];
    }
}

__global__ void scanc_k(const int* __restrict__ gcnt, int* __restrict__ colbase,
                        int* __restrict__ row_ptr) {
    __shared__ int sh[NR2];
    int v = gcnt[threadIdx.x];
    sh[threadIdx.x] = v;
    __syncthreads();
    for (int off = 1; off < NR2; off <<= 1) {
        int t = (threadIdx.x >= off) ? sh[threadIdx.x - off] : 0;
        __syncthreads();
        sh[threadIdx.x] += t;
        __syncthreads();
    }
    colbase[threadIdx.x] = sh[threadIdx.x] - v;  // exclusive
    if (threadIdx.x == 0) row_ptr[N_NODES] = N_EDGES;
}

__global__ __launch_bounds__(256) void csort_k(const unsigned* __restrict__ gbuf,
                                               const int* __restrict__ gcnt,
                                               const int* __restrict__ colbase,
                                               int* __restrict__ row_ptr,
                                               int* __restrict__ col) {
    __shared__ int sorted[PCAP2];   // 32 KB
    __shared__ int hist[512];
    __shared__ int cnt[512];
    __shared__ int run[400];
    const int q = blockIdx.x;
    const int tid = threadIdx.x;
    const int n2 = gcnt[q];
    const int cb = colbase[q];
    const int node0 = q * RANGE2;
    const unsigned* buf = gbuf + (size_t)q * PCAP2;

    hist[tid] = 0; hist[tid + 256] = 0;
    __syncthreads();
    for (int i = tid; i < n2; i += 256)
        atomicAdd(&hist[buf[i] >> 17], 1);
    __syncthreads();
    cnt[tid] = hist[tid];
    cnt[tid + 256] = hist[tid + 256];
    __syncthreads();
    for (int off = 1; off < 512; off <<= 1) {
        int v0 = (tid >= off) ? hist[tid - off] : 0;
        int v1 = hist[tid + 256 - off];
        __syncthreads();
        hist[tid] += v0;
        hist[tid + 256] += v1;
        __syncthreads();
    }
#pragma unroll
    for (int b = 0; b < 2; b++) {
        int i = tid + 256 * b;
        if (i < RANGE2) {
            int excl = hist[i] - cnt[i];
            run[i] = excl;
            int node = node0 + i;
            if (node < N_NODES) row_ptr[node] = cb + excl;
        }
    }
    __syncthreads();
    for (int i = tid; i < n2; i += 256) {
        unsigned w = buf[i];
        int pos = atomicAdd(&run[w >> 17], 1);
        sorted[pos] = (int)(w & 0x1FFFF);
    }
    __syncthreads();
    for (int i = tid; i < n2; i += 256) col[cb + i] = sorted[i];
}

// ---------------------------------------------------------------------------
// fp32 -> bf16 cast of x (layer-1 gather source)
// ---------------------------------------------------------------------------
__global__ __launch_bounds__(256) void cast_k(const float* __restrict__ x,
                                              unsigned short* __restrict__ hb) {
    int i = blockIdx.x * blockDim.x + threadIdx.x;  // float4 index
    if (i < N_NODES * (HID / 4)) {
        float4 v = ((const float4*)x)[i];
        us4 o = {f2bf(v.x), f2bf(v.y), f2bf(v.z), f2bf(v.w)};
        ((us4*)hb)[i] = o;
    }
}

// ---------------------------------------------------------------------------
// Weight pre-pack into MFMA B-fragment order (bf16, hi only).
// ---------------------------------------------------------------------------
__global__ void wsplit_k(const float* __restrict__ Wa, const float* __restrict__ Wb,
                         unsigned short* __restrict__ Whp) {
    int f = blockIdx.x * blockDim.x + threadIdx.x;
    if (f >= 6 * 16384) return;
    int g = f >> 14;
    int r = f & 16383;
    int j = r & 7;
    int L = (r >> 3) & 63;
    int t = r >> 9;          // kb*8 + nt
    int kb = t >> 3, nt = t & 7;
    int k = kb * 32 + ((L >> 4) & 3) * 8 + j;
    int n = nt * 16 + (L & 15);
    int layer = g >> 1;
    const float* W = (g & 1) ? Wb : Wa;
    Whp[f] = f2bf(W[layer * 16384 + k * 128 + n]);
}

// fcW [128][10] -> B-frag layout, N padded to 16 (bf16 hi only).
__global__ void fcsplit_k(const float* __restrict__ fcW,
                          unsigned short* __restrict__ fcWph) {
    int f = blockIdx.x * blockDim.x + threadIdx.x;
    if (f >= 2048) return;
    int j = f & 7;
    int L = (f >> 3) & 63;
    int kb = f >> 9;
    int k = kb * 32 + ((L >> 4) & 3) * 8 + j;
    int n = L & 15;
    fcWph[f] = f2bf((n < N_CLASS) ? fcW[k * N_CLASS + n] : 0.f);
}

// ---------------------------------------------------------------------------
// Aggregation: one HALF-WAVE (32 lanes) per node, bf16 rows (256B), us4/lane.
// fp32 accumulate. z[n] = h[n] + sum_{s in N(n)} h[s]
// ---------------------------------------------------------------------------
__global__ __launch_bounds__(256) void agg_k(const unsigned short* __restrict__ h,
                                             const int* __restrict__ row_ptr,
                                             const int* __restrict__ col,
                                             float* __restrict__ z) {
    const int half = (blockIdx.x * blockDim.x + threadIdx.x) >> 5;  // node id
    const int lane = threadIdx.x & 31;
    const int halfbase = threadIdx.x & 32;
    if (half >= N_NODES) return;
    const us4* hp = (const us4*)h;  // 32 x us4 per row
    float4 acc = us4f(hp[(size_t)half * 32 + lane]);  // self term, (1+eps)=1
    const int beg = row_ptr[half];
    const int end = row_ptr[half + 1];

    for (int base = beg; base < end; base += 32) {
        const int n = min(32, end - base);
        int myidx = (lane < n) ? col[base + lane] : 0;
        int j = 0;
        for (; j + 4 <= n; j += 4) {
            int i0 = __shfl(myidx, halfbase + j + 0, 64);
            int i1 = __shfl(myidx, halfbase + j + 1, 64);
            int i2 = __shfl(myidx, halfbase + j + 2, 64);
            int i3 = __shfl(myidx, halfbase + j + 3, 64);
            float4 v0 = us4f(hp[(size_t)i0 * 32 + lane]);
            float4 v1 = us4f(hp[(size_t)i1 * 32 + lane]);
            float4 v2 = us4f(hp[(size_t)i2 * 32 + lane]);
            float4 v3 = us4f(hp[(size_t)i3 * 32 + lane]);
            acc.x += v0.x; acc.y += v0.y; acc.z += v0.z; acc.w += v0.w;
            acc.x += v1.x; acc.y += v1.y; acc.z += v1.z; acc.w += v1.w;
            acc.x += v2.x; acc.y += v2.y; acc.z += v2.z; acc.w += v2.w;
            acc.x += v3.x; acc.y += v3.y; acc.z += v3.z; acc.w += v3.w;
        }
        for (; j < n; j++) {
            int i0 = __shfl(myidx, halfbase + j, 64);
            float4 v0 = us4f(hp[(size_t)i0 * 32 + lane]);
            acc.x += v0.x; acc.y += v0.y; acc.z += v0.z; acc.w += v0.w;
        }
    }
    ((float4*)z)[(size_t)half * 32 + lane] = acc;  // fp32 out, 32 float4/row
}

// ---------------------------------------------------------------------------
// MFMA MLP (single-term bf16, fp32 accumulate):
//   h_out = ELU(ELU(z@Wa + ba)@Wb + bb); mlp3 fuses the final FC.
// A-frag in LDS (16 KB); W read from global (L1/L2-broadcast).
// ---------------------------------------------------------------------------
__device__ __forceinline__ void gemm_phase(
    const unsigned short* Aph_,
    const unsigned short* __restrict__ Whi_g,
    const float* __restrict__ bias, int tid, f32x4 acc[2][4]) {
    const int L = tid & 63;
    const int w = tid >> 6;
    const int mt0 = (w >> 1) * 2;
    const int nt0 = (w & 1) * 4;
    const int lan15 = L & 15;
#pragma unroll
    for (int n = 0; n < 4; n++) {
        float b = bias[(nt0 + n) * 16 + lan15];
        f32x4 bv = {b, b, b, b};
        acc[0][n] = bv;
        acc[1][n] = bv;
    }
#pragma unroll
    for (int kb = 0; kb < 4; kb++) {
        short8 ah0 = *(const short8*)&Aph_[(((mt0 + 0) * 4 + kb) * 64 + L) * 8];
        short8 ah1 = *(const short8*)&Aph_[(((mt0 + 1) * 4 + kb) * 64 + L) * 8];
#pragma unroll
        for (int n = 0; n < 4; n++) {
            int widx = ((kb * 8 + nt0 + n) * 64 + L) * 8;
            short8 bh = *(const short8*)&Whi_g[widx];
            acc[0][n] = __builtin_amdgcn_mfma_f32_16x16x32_bf16(ah0, bh, acc[0][n], 0, 0, 0);
            acc[1][n] = __builtin_amdgcn_mfma_f32_16x16x32_bf16(ah1, bh, acc[1][n], 0, 0, 0);
        }
    }
}

// shared body: FC==0 -> store bf16 h to hout; FC==1 -> fused final FC to out
template <int FC>
__device__ __forceinline__ void mlp_body(
    const float* __restrict__ zin,
    const unsigned short* __restrict__ Wahp,
    const unsigned short* __restrict__ Wbhp,
    const float* __restrict__ ba, const float* __restrict__ bb,
    unsigned short* __restrict__ hout,
    const unsigned short* __restrict__ fcWph,
    const float* __restrict__ fcb, float* __restrict__ out) {
    __shared__ unsigned short Aph[8192];   // 16 KB: packed A (bf16)

    const int tid = threadIdx.x;
    const int L = tid & 63;
    const int w = tid >> 6;
    const int mt0 = (w >> 1) * 2;
    const int nt0 = (w & 1) * 4;
    const int lan15 = L & 15;
    const int quad = L >> 4;
    const size_t node_base = (size_t)blockIdx.x * 64;

    // ---- phase A: load z tile, round to bf16, pack to A-frag layout ----
    {
        const float4* zin4 = (const float4*)(zin + node_base * HID);
#pragma unroll
        for (int r = 0; r < 8; r++) {
            int f = tid + 256 * r;          // [0, 2048)
            int m = f >> 5;
            int k0 = (f & 31) * 4;
            float4 zv = zin4[f];
            int kb = k0 >> 5;
            int q = (k0 & 31) >> 3;
            int j0 = k0 & 7;                 // 0 or 4
            int idx = (((m >> 4) * 4 + kb) * 64 + ((m & 15) + 16 * q)) * 8 + j0;
            us4 h4 = {f2bf(zv.x), f2bf(zv.y), f2bf(zv.z), f2bf(zv.w)};
            *(us4*)&Aph[idx] = h4;
        }
    }
    __syncthreads();

    // ---- GEMM1: t = ELU(z @ Wa + ba) ----
    {
        f32x4 acc[2][4];
        gemm_phase(Aph, Wahp, ba, tid, acc);
        __syncthreads();
#pragma unroll
        for (int i = 0; i < 2; i++) {
#pragma unroll
            for (int n = 0; n < 4; n++) {
                int kdim = (nt0 + n) * 16 + lan15;
                int kb2 = kdim >> 5;
                int q2 = (kdim & 31) >> 3;
                int j2 = kdim & 7;
#pragma unroll
                for (int r = 0; r < 4; r++) {
                    float v = elu(acc[i][n][r]);
                    int mrow = quad * 4 + r;
                    int idx = (((mt0 + i) * 4 + kb2) * 64 + (mrow + 16 * q2)) * 8 + j2;
                    Aph[idx] = f2bf(v);
                }
            }
        }
    }
    __syncthreads();

    // ---- GEMM2: h = ELU(t @ Wb + bb) ----
    {
        f32x4 acc[2][4];
        gemm_phase(Aph, Wbhp, bb, tid, acc);
        if (FC == 0) {
#pragma unroll
            for (int i = 0; i < 2; i++) {
#pragma unroll
                for (int n = 0; n < 4; n++) {
                    int ncol = (nt0 + n) * 16 + lan15;
#pragma unroll
                    for (int r = 0; r < 4; r++) {
                        int mrow = (mt0 + i) * 16 + quad * 4 + r;
                        hout[(node_base + mrow) * HID + ncol] = f2bf(elu(acc[i][n][r]));
                    }
                }
            }
        } else {
            // repack h (bf16, identical rounding to the stored-h path) for FC
            __syncthreads();
#pragma unroll
            for (int i = 0; i < 2; i++) {
#pragma unroll
                for (int n = 0; n < 4; n++) {
                    int kdim = (nt0 + n) * 16 + lan15;
                    int kb2 = kdim >> 5;
                    int q2 = (kdim & 31) >> 3;
                    int j2 = kdim & 7;
#pragma unroll
                    for (int r = 0; r < 4; r++) {
                        float v = elu(acc[i][n][r]);
                        int mrow = quad * 4 + r;
                        int idx = (((mt0 + i) * 4 + kb2) * 64 + (mrow + 16 * q2)) * 8 + j2;
                        Aph[idx] = f2bf(v);
                    }
                }
            }
            __syncthreads();
            // FC: waves 0 and 2 handle their 2 M-tiles vs N-tile 0
            if ((w & 1) == 0) {
#pragma unroll
                for (int i = 0; i < 2; i++) {
                    int mt = mt0 + i;
                    float b = (lan15 < N_CLASS) ? fcb[lan15] : 0.f;
                    f32x4 acc2 = {b, b, b, b};
#pragma unroll
                    for (int kb = 0; kb < 4; kb++) {
                        short8 a = *(const short8*)&Aph[((mt * 4 + kb) * 64 + L) * 8];
                        short8 bh = *(const short8*)&fcWph[(kb * 64 + L) * 8];
                        acc2 = __builtin_amdgcn_mfma_f32_16x16x32_bf16(a, bh, acc2, 0, 0, 0);
                    }
#pragma unroll
                    for (int r = 0; r < 4; r++) {
                        size_t node = node_base + mt * 16 + quad * 4 + r;
                        if (node < N_NODES && lan15 < N_CLASS)
                            out[node * N_CLASS + lan15] = acc2[r];
                    }
                }
            }
        }
    }
}

__global__ __launch_bounds__(256) void mlp2_k(
    const float* __restrict__ zin,
    const unsigned short* __restrict__ Wahp,
    const unsigned short* __restrict__ Wbhp,
    const float* __restrict__ ba, const float* __restrict__ bb,
    unsigned short* __restrict__ hout) {
    mlp_body<0>(zin, Wahp, Wbhp, ba, bb, hout, nullptr, nullptr, nullptr);
}

__global__ __launch_bounds__(256) void mlp3_k(
    const float* __restrict__ zin,
    const unsigned short* __restrict__ Wahp,
    const unsigned short* __restrict__ Wbhp,
    const float* __restrict__ ba, const float* __restrict__ bb,
    const unsigned short* __restrict__ fcWph,
    const float* __restrict__ fcb, float* __restrict__ out) {
    mlp_body<1>(zin, Wahp, Wbhp, ba, bb, nullptr, fcWph, fcb, out);
}

// ---------------------------------------------------------------------------

extern "C" void kernel_launch(void* const* d_in, const int* in_sizes, int n_in,
                              void* d_out, int out_size, void* d_ws, size_t ws_size,
                              hipStream_t stream) {
    const float* x = (const float*)d_in[0];
    const int* ei = (const int*)d_in[1];  // [2][E]
    // d_in[2] = edge_weight (unused by the reference forward)
    const float* Wa = (const float*)d_in[3];   // [3][128][128]
    const float* ba = (const float*)d_in[4];   // [3][128]
    const float* Wb = (const float*)d_in[5];
    const float* bb = (const float*)d_in[6];
    const float* fcW = (const float*)d_in[7];  // [128][10]
    const float* fcb = (const float*)d_in[8];  // [10]
    float* out = (float*)d_out;

    const int* src = ei;
    const int* dst = ei + N_EDGES;

    // workspace carve
    char* w = (char*)d_ws;
    float* zbuf = (float*)w;          w += (size_t)N_PAD * HID * 4;  // fp32 agg out
    unsigned short* hb = (unsigned short*)w; w += (size_t)N_PAD * HID * 2;  // bf16 h
    int* row_ptr = (int*)w;  w += ((size_t)N_NODES + 8) * 4;
    int* gcnt = (int*)w;     w += NR2 * 4;
    int* colbase = (int*)w;  w += NR2 * 4;
    int* col = (int*)w;      w += (size_t)N_EDGES * 4;
    unsigned short* Whp = (unsigned short*)w; w += 6 * 16384 * 2;
    unsigned short* fcWph = (unsigned short*)w; w += 2048 * 2;
    unsigned* gbuf = (unsigned*)w; w += (size_t)NR2 * PCAP2 * 4;  // 8 MB

    // ---- weight pack + x cast (independent of CSR) ----
    wsplit_k<<<(6 * 16384 + 255) / 256, 256, 0, stream>>>(Wa, Wb, Whp);
    fcsplit_k<<<8, 256, 0, stream>>>(fcW, fcWph);
    cast_k<<<(N_NODES * (HID / 4) + 255) / 256, 256, 0, stream>>>(x, hb);

    // ---- CSR build v3 ----
    hipMemsetAsync(gcnt, 0, NR2 * 4, stream);
    part_k<<<P_BLOCKS, 256, 0, stream>>>(src, dst, gcnt, gbuf);
    scanc_k<<<1, 256, 0, stream>>>(gcnt, colbase, row_ptr);
    csort_k<<<NR2, 256, 0, stream>>>(gbuf, gcnt, colbase, row_ptr, col);

    const int AGG_BLOCKS = (N_NODES * 32 + 255) / 256;  // one half-wave per node
    const int MLP_BLOCKS = (N_NODES + 63) / 64;         // 1563 (ws rows padded)

    // ---- layer 1 ----
    agg_k<<<AGG_BLOCKS, 256, 0, stream>>>(hb, row_ptr, col, zbuf);
    mlp2_k<<<MLP_BLOCKS, 256, 0, stream>>>(zbuf, Whp, Whp + 16384, ba, bb, hb);
    // ---- layer 2 ----
    agg_k<<<AGG_BLOCKS, 256, 0, stream>>>(hb, row_ptr, col, zbuf);
    mlp2_k<<<MLP_BLOCKS, 256, 0, stream>>>(zbuf, Whp + 2 * 16384, Whp + 3 * 16384,
                                           ba + 128, bb + 128, hb);
    // ---- layer 3: MLP + fused final FC ----
    agg_k<<<AGG_BLOCKS, 256, 0, stream>>>(hb, row_ptr, col, zbuf);
    mlp3_k<<<MLP_BLOCKS, 256, 0, stream>>>(zbuf, Whp + 4 * 16384, Whp + 5 * 16384,
                                           ba + 256, bb + 256,
                                           fcWph, fcb, out);
}

// Round 10
// 402.503 us; speedup vs baseline: 1.1720x; 1.0421x over previous
//
#include <hip/hip_runtime.h>
#include <hip/hip_bf16.h>
#include <math.h>

#define N_NODES 100000
#define N_PAD 100032   // padded row count for workspace feature buffers
#define N_EDGES 1600000
#define HID 128
#define N_CLASS 10

// edge partition params: 256 dst-ranges of 391 nodes (256*391 = 100096)
#define NR2 256
#define RANGE2 391
#define PCAP2 8192     // per-range packed capacity (expected ~6250)
#define P_BLOCKS 512
#define P_SLICE (N_EDGES / P_BLOCKS)  // 3125
#define CAST_ITEMS (N_NODES * (HID / 4))   // 3.2M float4 units
#define CAST_BLOCKS ((CAST_ITEMS + 2047) / 2048)  // 1563
#define WSPLIT_BLOCKS 384                  // 6*16384/256

typedef float f32x4 __attribute__((ext_vector_type(4)));
typedef short short8 __attribute__((ext_vector_type(8)));
typedef unsigned short us4 __attribute__((ext_vector_type(4)));

// bf16 helpers (round-to-nearest-even)
__device__ __forceinline__ unsigned short f2bf(float x) {
    unsigned u = __float_as_uint(x);
    unsigned r = u + 0x7FFF + ((u >> 16) & 1);
    return (unsigned short)(r >> 16);
}
__device__ __forceinline__ float bf2f(unsigned short h) {
    return __uint_as_float(((unsigned)h) << 16);
}
__device__ __forceinline__ float elu(float x) {
    return x > 0.f ? x : (expf(x) - 1.f);
}
__device__ __forceinline__ float4 us4f(us4 v) {
    float4 o;
    o.x = bf2f(v.x); o.y = bf2f(v.y); o.z = bf2f(v.z); o.w = bf2f(v.w);
    return o;
}

// ---------------------------------------------------------------------------
// setup_k: fused edge-partition + x-cast + weight-pack (block-range dispatch).
//   blocks [0,512): 256-way dst-range partition of edges (packed src|dloc<<17)
//   blocks [512,2075): fp32->bf16 cast of x
//   blocks [2075,2459): MLP weight pack to B-frag layout
//   block 2459: fcW pack + row_ptr[N]=E
// gcnt must be zeroed before this kernel (hipMemsetAsync).
// ---------------------------------------------------------------------------
__global__ __launch_bounds__(256) void setup_k(
    const int* __restrict__ src, const int* __restrict__ dst,
    int* __restrict__ gcnt, unsigned* __restrict__ gbuf,
    const float* __restrict__ x, unsigned short* __restrict__ hb,
    const float* __restrict__ Wa, const float* __restrict__ Wb,
    unsigned short* __restrict__ Whp,
    const float* __restrict__ fcW, unsigned short* __restrict__ fcWph,
    int* __restrict__ row_ptr) {
    __shared__ unsigned stash[P_SLICE];
    __shared__ unsigned char rbuf[P_SLICE];
    __shared__ int hist[NR2], cur[NR2], base[NR2];
    const int b = blockIdx.x;
    const int tid = threadIdx.x;

    if (b < P_BLOCKS) {
        // ---- edge partition ----
        hist[tid] = 0;
        cur[tid] = 0;
        __syncthreads();
        const int e0 = b * P_SLICE;
        for (int i = tid; i < P_SLICE; i += 256) {
            unsigned s = (unsigned)src[e0 + i];
            unsigned d = (unsigned)dst[e0 + i];
            unsigned r = d / RANGE2;            // magic-mul
            unsigned dloc = d - r * RANGE2;     // < 391 (9 bits)
            stash[i] = s | (dloc << 17);
            rbuf[i] = (unsigned char)r;
            atomicAdd(&hist[r], 1);
        }
        __syncthreads();
        base[tid] = atomicAdd(&gcnt[tid], hist[tid]);
        __syncthreads();
        for (int i = tid; i < P_SLICE; i += 256) {
            unsigned r = rbuf[i];
            int off = atomicAdd(&cur[r], 1);
            int pos = base[r] + off;
            if (pos < PCAP2) gbuf[(size_t)r * PCAP2 + pos] = stash[i];
        }
    } else if (b < P_BLOCKS + CAST_BLOCKS) {
        // ---- x cast ----
        const int cb = b - P_BLOCKS;
#pragma unroll
        for (int it = 0; it < 8; it++) {
            int i = cb * 2048 + it * 256 + tid;
            if (i < CAST_ITEMS) {
                float4 v = ((const float4*)x)[i];
                us4 o = {f2bf(v.x), f2bf(v.y), f2bf(v.z), f2bf(v.w)};
                ((us4*)hb)[i] = o;
            }
        }
    } else if (b < P_BLOCKS + CAST_BLOCKS + WSPLIT_BLOCKS) {
        // ---- MLP weight pack ----
        int f = (b - P_BLOCKS - CAST_BLOCKS) * 256 + tid;  // < 98304
        int g = f >> 14;
        int r = f & 16383;
        int j = r & 7;
        int L = (r >> 3) & 63;
        int t = r >> 9;
        int kb = t >> 3, nt = t & 7;
        int k = kb * 32 + ((L >> 4) & 3) * 8 + j;
        int n = nt * 16 + (L & 15);
        int layer = g >> 1;
        const float* W = (g & 1) ? Wb : Wa;
        Whp[f] = f2bf(W[layer * 16384 + k * 128 + n]);
    } else {
        // ---- fcW pack + row_ptr tail ----
#pragma unroll
        for (int it = 0; it < 8; it++) {
            int f = it * 256 + tid;  // < 2048
            int j = f & 7;
            int L = (f >> 3) & 63;
            int kb = f >> 9;
            int k = kb * 32 + ((L >> 4) & 3) * 8 + j;
            int n = L & 15;
            fcWph[f] = f2bf((n < N_CLASS) ? fcW[k * N_CLASS + n] : 0.f);
        }
        if (tid == 0) row_ptr[N_NODES] = N_EDGES;
    }
}

// ---------------------------------------------------------------------------
// csort_k: per-range LDS counting sort (self-scans gcnt for col bases).
// row_ptr written here; col written sequentially in full lines.
// ---------------------------------------------------------------------------
__global__ __launch_bounds__(256) void csort_k(const unsigned* __restrict__ gbuf,
                                               const int* __restrict__ gcnt,
                                               int* __restrict__ row_ptr,
                                               int* __restrict__ col) {
    __shared__ int sorted[PCAP2];   // 32 KB
    __shared__ int hist[512];
    __shared__ int cnt[512];
    __shared__ int run[400];
    __shared__ int gsc[NR2];
    const int q = blockIdx.x;
    const int tid = threadIdx.x;

    // self-scan of gcnt -> col base for this range
    gsc[tid] = gcnt[tid];
    __syncthreads();
    for (int off = 1; off < NR2; off <<= 1) {
        int t = (tid >= off) ? gsc[tid - off] : 0;
        __syncthreads();
        gsc[tid] += t;
        __syncthreads();
    }
    const int cb = (q > 0) ? gsc[q - 1] : 0;   // exclusive prefix
    const int n2 = gcnt[q];
    const int node0 = q * RANGE2;
    const unsigned* buf = gbuf + (size_t)q * PCAP2;

    hist[tid] = 0; hist[tid + 256] = 0;
    __syncthreads();
    for (int i = tid; i < n2; i += 256)
        atomicAdd(&hist[buf[i] >> 17], 1);
    __syncthreads();
    cnt[tid] = hist[tid];
    cnt[tid + 256] = hist[tid + 256];
    __syncthreads();
    for (int off = 1; off < 512; off <<= 1) {
        int v0 = (tid >= off) ? hist[tid - off] : 0;
        int v1 = hist[tid + 256 - off];
        __syncthreads();
        hist[tid] += v0;
        hist[tid + 256] += v1;
        __syncthreads();
    }
#pragma unroll
    for (int bb = 0; bb < 2; bb++) {
        int i = tid + 256 * bb;
        if (i < RANGE2) {
            int excl = hist[i] - cnt[i];
            run[i] = excl;
            int node = node0 + i;
            if (node < N_NODES) row_ptr[node] = cb + excl;
        }
    }
    __syncthreads();
    for (int i = tid; i < n2; i += 256) {
        unsigned w = buf[i];
        int pos = atomicAdd(&run[w >> 17], 1);
        sorted[pos] = (int)(w & 0x1FFFF);
    }
    __syncthreads();
    for (int i = tid; i < n2; i += 256) col[cb + i] = sorted[i];
}

// ---------------------------------------------------------------------------
// Aggregation: one HALF-WAVE (32 lanes) per node, bf16 rows, fp32 accumulate,
// bf16 output rows (RNE — identical rounding to the old mlp phase A).
// ---------------------------------------------------------------------------
__global__ __launch_bounds__(256) void agg_k(const unsigned short* __restrict__ h,
                                             const int* __restrict__ row_ptr,
                                             const int* __restrict__ col,
                                             unsigned short* __restrict__ z) {
    const int half = (blockIdx.x * blockDim.x + threadIdx.x) >> 5;  // node id
    const int lane = threadIdx.x & 31;
    const int halfbase = threadIdx.x & 32;
    if (half >= N_NODES) return;
    const us4* hp = (const us4*)h;  // 32 x us4 per row
    float4 acc = us4f(hp[(size_t)half * 32 + lane]);  // self term, (1+eps)=1
    const int beg = row_ptr[half];
    const int end = row_ptr[half + 1];

    for (int base = beg; base < end; base += 32) {
        const int n = min(32, end - base);
        int myidx = (lane < n) ? col[base + lane] : 0;
        int j = 0;
        for (; j + 4 <= n; j += 4) {
            int i0 = __shfl(myidx, halfbase + j + 0, 64);
            int i1 = __shfl(myidx, halfbase + j + 1, 64);
            int i2 = __shfl(myidx, halfbase + j + 2, 64);
            int i3 = __shfl(myidx, halfbase + j + 3, 64);
            float4 v0 = us4f(hp[(size_t)i0 * 32 + lane]);
            float4 v1 = us4f(hp[(size_t)i1 * 32 + lane]);
            float4 v2 = us4f(hp[(size_t)i2 * 32 + lane]);
            float4 v3 = us4f(hp[(size_t)i3 * 32 + lane]);
            acc.x += v0.x; acc.y += v0.y; acc.z += v0.z; acc.w += v0.w;
            acc.x += v1.x; acc.y += v1.y; acc.z += v1.z; acc.w += v1.w;
            acc.x += v2.x; acc.y += v2.y; acc.z += v2.z; acc.w += v2.w;
            acc.x += v3.x; acc.y += v3.y; acc.z += v3.z; acc.w += v3.w;
        }
        for (; j < n; j++) {
            int i0 = __shfl(myidx, halfbase + j, 64);
            float4 v0 = us4f(hp[(size_t)i0 * 32 + lane]);
            acc.x += v0.x; acc.y += v0.y; acc.z += v0.z; acc.w += v0.w;
        }
    }
    us4 o = {f2bf(acc.x), f2bf(acc.y), f2bf(acc.z), f2bf(acc.w)};
    ((us4*)z)[(size_t)half * 32 + lane] = o;   // bf16 row, 256B coalesced
}

// ---------------------------------------------------------------------------
// MFMA MLP (single-term bf16, fp32 accumulate):
//   h_out = ELU(ELU(z@Wa + ba)@Wb + bb); mlp3 fuses the final FC.
// GEMM1 reads A-frags DIRECTLY from global bf16 z rows (64B-coalesced,
// L2-hit); LDS (16 KB) only stages the t repack for GEMM2.
// ---------------------------------------------------------------------------
__device__ __forceinline__ void gemm1_g(
    const unsigned short* __restrict__ zrow,   // block-base z row pointer
    const unsigned short* __restrict__ Whi_g,
    const float* __restrict__ bias, int tid, f32x4 acc[2][4]) {
    const int L = tid & 63;
    const int w = tid >> 6;
    const int mt0 = (w >> 1) * 2;
    const int nt0 = (w & 1) * 4;
    const int lan15 = L & 15;
    const int quad = L >> 4;
#pragma unroll
    for (int n = 0; n < 4; n++) {
        float b = bias[(nt0 + n) * 16 + lan15];
        f32x4 bv = {b, b, b, b};
        acc[0][n] = bv;
        acc[1][n] = bv;
    }
    const unsigned short* rowA0 = zrow + (mt0 * 16 + lan15) * HID + quad * 8;
    const unsigned short* rowA1 = rowA0 + 16 * HID;
#pragma unroll
    for (int kb = 0; kb < 4; kb++) {
        short8 ah0 = *(const short8*)&rowA0[kb * 32];
        short8 ah1 = *(const short8*)&rowA1[kb * 32];
#pragma unroll
        for (int n = 0; n < 4; n++) {
            short8 bh = *(const short8*)&Whi_g[((kb * 8 + nt0 + n) * 64 + L) * 8];
            acc[0][n] = __builtin_amdgcn_mfma_f32_16x16x32_bf16(ah0, bh, acc[0][n], 0, 0, 0);
            acc[1][n] = __builtin_amdgcn_mfma_f32_16x16x32_bf16(ah1, bh, acc[1][n], 0, 0, 0);
        }
    }
}

__device__ __forceinline__ void gemm_lds(
    const unsigned short* Aph_,
    const unsigned short* __restrict__ Whi_g,
    const float* __restrict__ bias, int tid, f32x4 acc[2][4]) {
    const int L = tid & 63;
    const int w = tid >> 6;
    const int mt0 = (w >> 1) * 2;
    const int nt0 = (w & 1) * 4;
    const int lan15 = L & 15;
#pragma unroll
    for (int n = 0; n < 4; n++) {
        float b = bias[(nt0 + n) * 16 + lan15];
        f32x4 bv = {b, b, b, b};
        acc[0][n] = bv;
        acc[1][n] = bv;
    }
#pragma unroll
    for (int kb = 0; kb < 4; kb++) {
        short8 ah0 = *(const short8*)&Aph_[(((mt0 + 0) * 4 + kb) * 64 + L) * 8];
        short8 ah1 = *(const short8*)&Aph_[(((mt0 + 1) * 4 + kb) * 64 + L) * 8];
#pragma unroll
        for (int n = 0; n < 4; n++) {
            short8 bh = *(const short8*)&Whi_g[((kb * 8 + nt0 + n) * 64 + L) * 8];
            acc[0][n] = __builtin_amdgcn_mfma_f32_16x16x32_bf16(ah0, bh, acc[0][n], 0, 0, 0);
            acc[1][n] = __builtin_amdgcn_mfma_f32_16x16x32_bf16(ah1, bh, acc[1][n], 0, 0, 0);
        }
    }
}

template <int FC>
__device__ __forceinline__ void mlp_body(
    const unsigned short* __restrict__ zb,
    const unsigned short* __restrict__ Wahp,
    const unsigned short* __restrict__ Wbhp,
    const float* __restrict__ ba, const float* __restrict__ bb,
    unsigned short* __restrict__ hout,
    const unsigned short* __restrict__ fcWph,
    const float* __restrict__ fcb, float* __restrict__ out) {
    __shared__ unsigned short Aph[8192];   // 16 KB: packed t (bf16)

    const int tid = threadIdx.x;
    const int L = tid & 63;
    const int w = tid >> 6;
    const int mt0 = (w >> 1) * 2;
    const int nt0 = (w & 1) * 4;
    const int lan15 = L & 15;
    const int quad = L >> 4;
    const size_t node_base = (size_t)blockIdx.x * 64;

    // ---- GEMM1: t = ELU(z @ Wa + ba), A straight from global z rows ----
    {
        f32x4 acc[2][4];
        gemm1_g(zb + node_base * HID, Wahp, ba, tid, acc);
        // repack t (bf16) into A-frag LDS; writes are wave-disjoint
#pragma unroll
        for (int i = 0; i < 2; i++) {
#pragma unroll
            for (int n = 0; n < 4; n++) {
                int kdim = (nt0 + n) * 16 + lan15;
                int kb2 = kdim >> 5;
                int q2 = (kdim & 31) >> 3;
                int j2 = kdim & 7;
#pragma unroll
                for (int r = 0; r < 4; r++) {
                    float v = elu(acc[i][n][r]);
                    int mrow = quad * 4 + r;
                    int idx = (((mt0 + i) * 4 + kb2) * 64 + (mrow + 16 * q2)) * 8 + j2;
                    Aph[idx] = f2bf(v);
                }
            }
        }
    }
    __syncthreads();

    // ---- GEMM2: h = ELU(t @ Wb + bb) ----
    {
        f32x4 acc[2][4];
        gemm_lds(Aph, Wbhp, bb, tid, acc);
        if (FC == 0) {
#pragma unroll
            for (int i = 0; i < 2; i++) {
#pragma unroll
                for (int n = 0; n < 4; n++) {
                    int ncol = (nt0 + n) * 16 + lan15;
#pragma unroll
                    for (int r = 0; r < 4; r++) {
                        int mrow = (mt0 + i) * 16 + quad * 4 + r;
                        hout[(node_base + mrow) * HID + ncol] = f2bf(elu(acc[i][n][r]));
                    }
                }
            }
        } else {
            // repack h (bf16, identical rounding to stored-h path) for FC
            __syncthreads();
#pragma unroll
            for (int i = 0; i < 2; i++) {
#pragma unroll
                for (int n = 0; n < 4; n++) {
                    int kdim = (nt0 + n) * 16 + lan15;
                    int kb2 = kdim >> 5;
                    int q2 = (kdim & 31) >> 3;
                    int j2 = kdim & 7;
#pragma unroll
                    for (int r = 0; r < 4; r++) {
                        float v = elu(acc[i][n][r]);
                        int mrow = quad * 4 + r;
                        int idx = (((mt0 + i) * 4 + kb2) * 64 + (mrow + 16 * q2)) * 8 + j2;
                        Aph[idx] = f2bf(v);
                    }
                }
            }
            __syncthreads();
            // FC: waves 0 and 2 handle their 2 M-tiles vs N-tile 0
            if ((w & 1) == 0) {
#pragma unroll
                for (int i = 0; i < 2; i++) {
                    int mt = mt0 + i;
                    float b = (lan15 < N_CLASS) ? fcb[lan15] : 0.f;
                    f32x4 acc2 = {b, b, b, b};
#pragma unroll
                    for (int kb = 0; kb < 4; kb++) {
                        short8 a = *(const short8*)&Aph[((mt * 4 + kb) * 64 + L) * 8];
                        short8 bh = *(const short8*)&fcWph[(kb * 64 + L) * 8];
                        acc2 = __builtin_amdgcn_mfma_f32_16x16x32_bf16(a, bh, acc2, 0, 0, 0);
                    }
#pragma unroll
                    for (int r = 0; r < 4; r++) {
                        size_t node = node_base + mt * 16 + quad * 4 + r;
                        if (node < N_NODES && lan15 < N_CLASS)
                            out[node * N_CLASS + lan15] = acc2[r];
                    }
                }
            }
        }
    }
}

__global__ __launch_bounds__(256) void mlp2_k(
    const unsigned short* __restrict__ zb,
    const unsigned short* __restrict__ Wahp,
    const unsigned short* __restrict__ Wbhp,
    const float* __restrict__ ba, const float* __restrict__ bb,
    unsigned short* __restrict__ hout) {
    mlp_body<0>(zb, Wahp, Wbhp, ba, bb, hout, nullptr, nullptr, nullptr);
}

__global__ __launch_bounds__(256) void mlp3_k(
    const unsigned short* __restrict__ zb,
    const unsigned short* __restrict__ Wahp,
    const unsigned short* __restrict__ Wbhp,
    const float* __restrict__ ba, const float* __restrict__ bb,
    const unsigned short* __restrict__ fcWph,
    const float* __restrict__ fcb, float* __restrict__ out) {
    mlp_body<1>(zb, Wahp, Wbhp, ba, bb, nullptr, fcWph, fcb, out);
}

// ---------------------------------------------------------------------------

extern "C" void kernel_launch(void* const* d_in, const int* in_sizes, int n_in,
                              void* d_out, int out_size, void* d_ws, size_t ws_size,
                              hipStream_t stream) {
    const float* x = (const float*)d_in[0];
    const int* ei = (const int*)d_in[1];  // [2][E]
    // d_in[2] = edge_weight (unused by the reference forward)
    const float* Wa = (const float*)d_in[3];   // [3][128][128]
    const float* ba = (const float*)d_in[4];   // [3][128]
    const float* Wb = (const float*)d_in[5];
    const float* bb = (const float*)d_in[6];
    const float* fcW = (const float*)d_in[7];  // [128][10]
    const float* fcb = (const float*)d_in[8];  // [10]
    float* out = (float*)d_out;

    const int* src = ei;
    const int* dst = ei + N_EDGES;

    // workspace carve
    char* w = (char*)d_ws;
    unsigned short* zb = (unsigned short*)w; w += (size_t)N_PAD * HID * 2;  // bf16 z
    unsigned short* hb = (unsigned short*)w; w += (size_t)N_PAD * HID * 2;  // bf16 h
    int* row_ptr = (int*)w;  w += ((size_t)N_NODES + 8) * 4;
    int* gcnt = (int*)w;     w += NR2 * 4;
    int* col = (int*)w;      w += (size_t)N_EDGES * 4;
    unsigned short* Whp = (unsigned short*)w; w += 6 * 16384 * 2;
    unsigned short* fcWph = (unsigned short*)w; w += 2048 * 2;
    unsigned* gbuf = (unsigned*)w; w += (size_t)NR2 * PCAP2 * 4;  // 8 MB

    // ---- setup: partition + cast + weight pack (one fused kernel) ----
    hipMemsetAsync(gcnt, 0, NR2 * 4, stream);
    const int SETUP_BLOCKS = P_BLOCKS + CAST_BLOCKS + WSPLIT_BLOCKS + 1;
    setup_k<<<SETUP_BLOCKS, 256, 0, stream>>>(src, dst, gcnt, gbuf, x, hb,
                                              Wa, Wb, Whp, fcW, fcWph, row_ptr);
    // ---- counting sort -> CSR ----
    csort_k<<<NR2, 256, 0, stream>>>(gbuf, gcnt, row_ptr, col);

    const int AGG_BLOCKS = (N_NODES * 32 + 255) / 256;  // one half-wave per node
    const int MLP_BLOCKS = (N_NODES + 63) / 64;         // 1563 (ws rows padded)

    // ---- layer 1 ----
    agg_k<<<AGG_BLOCKS, 256, 0, stream>>>(hb, row_ptr, col, zb);
    mlp2_k<<<MLP_BLOCKS, 256, 0, stream>>>(zb, Whp, Whp + 16384, ba, bb, hb);
    // ---- layer 2 ----
    agg_k<<<AGG_BLOCKS, 256, 0, stream>>>(hb, row_ptr, col, zb);
    mlp2_k<<<MLP_BLOCKS, 256, 0, stream>>>(zb, Whp + 2 * 16384, Whp + 3 * 16384,
                                           ba + 128, bb + 128, hb);
    // ---- layer 3: MLP + fused final FC ----
    agg_k<<<AGG_BLOCKS, 256, 0, stream>>>(hb, row_ptr, col, zb);
    mlp3_k<<<MLP_BLOCKS, 256, 0, stream>>>(zb, Whp + 4 * 16384, Whp + 5 * 16384,
                                           ba + 256, bb + 256,
                                           fcWph, fcb, out);
}